// Round 6
// baseline (269.107 us; speedup 1.0000x reference)
//
#include <hip/hip_runtime.h>

#define B_ 2
#define T_ 2048
#define D_ 2048
#define H_ 16
#define KV_ 4
#define HD_ 128
#define M_ (B_*T_)   // 4096

typedef __attribute__((ext_vector_type(8))) short s8v;
typedef __attribute__((ext_vector_type(4))) float f4v;
typedef __attribute__((ext_vector_type(16))) float f16v;
typedef __attribute__((ext_vector_type(8))) __bf16 b8v;
typedef __attribute__((ext_vector_type(4))) unsigned u4v;

__device__ __forceinline__ short f2bs(float f) {
  unsigned u = __builtin_bit_cast(unsigned, f);
  u += 0x7fffu + ((u >> 16) & 1u);
  return (short)(u >> 16);
}
__device__ __forceinline__ unsigned pack2(float a, float b) {
  return (unsigned)(unsigned short)f2bs(a) | ((unsigned)(unsigned short)f2bs(b) << 16);
}

// ---------------- elementwise fp32 -> bf16 cast ----------------
__global__ void cast_bf16_kernel(const float* __restrict__ in, short* __restrict__ out, int n4) {
  int i = blockIdx.x * 256 + threadIdx.x;
  if (i >= n4) return;
  float4 v = reinterpret_cast<const float4*>(in)[i];
  short4 o;
  o.x = f2bs(v.x); o.y = f2bs(v.y); o.z = f2bs(v.z); o.w = f2bs(v.w);
  reinterpret_cast<short4*>(out)[i] = o;
}

// ---------------- transpose + cast: W[K][N] fp32 -> WT[N][K] bf16 ----------------
__global__ void tcast_kernel(const float* __restrict__ W, short* __restrict__ WT, int N, int K) {
  __shared__ float t[32][33];
  int tx = threadIdx.x, ty = threadIdx.y;
  int nb = blockIdx.x * 32, kb = blockIdx.y * 32;
#pragma unroll
  for (int j = 0; j < 4; ++j)
    t[ty + j*8][tx] = W[(size_t)(kb + ty + j*8) * N + nb + tx];
  __syncthreads();
#pragma unroll
  for (int j = 0; j < 4; ++j)
    WT[(size_t)(nb + ty + j*8) * K + kb + tx] = f2bs(t[tx][ty + j*8]);
}

// ---------------- GEMM: C[M][N] = A[M][K](bf16) * BT[N][K](bf16)^T ----------------
// MODE 0: bf16 row-major out. MODE 1: f32 row-major out.
// MODE 2: KV split — cols <512 -> K bf16 row-major [M][512] into Cv;
//                    cols >=512 -> V^T bf16 [512][M] into C2.
template<int MODE>
__global__ __launch_bounds__(256) void gemm_bt_kernel(const short* __restrict__ A,
                                                      const short* __restrict__ BT,
                                                      void* __restrict__ Cv,
                                                      short* __restrict__ C2,
                                                      int M, int N, int K) {
  __shared__ alignas(16) short As[128*32];
  __shared__ alignas(16) short Bs[128*32];
  const int tid  = threadIdx.x;
  const int wave = tid >> 6;
  const int lane = tid & 63;
  const int lr = lane & 15;
  const int lk = (lane >> 4) * 8;
  const int m0 = blockIdx.y * 128;
  const int n0 = blockIdx.x * 128;
  const int wr = (wave >> 1) * 64;
  const int wc = (wave & 1) * 64;

  f4v acc[4][4];
#pragma unroll
  for (int m = 0; m < 4; ++m)
#pragma unroll
    for (int n = 0; n < 4; ++n) acc[m][n] = (f4v)0.0f;

  for (int k0 = 0; k0 < K; k0 += 32) {
#pragma unroll
    for (int j = 0; j < 2; ++j) {
      const int f = j*256 + tid;
      const int row = f >> 2, kc = f & 3;
      const short* ga = A  + (size_t)(m0 + row) * K + k0 + kc*8;
      const short* gb = BT + (size_t)(n0 + row) * K + k0 + kc*8;
      short* la = As + (j*256 + wave*64) * 8;
      short* lb = Bs + (j*256 + wave*64) * 8;
      __builtin_amdgcn_global_load_lds((const __attribute__((address_space(1))) void*)ga,
                                       (__attribute__((address_space(3))) void*)la, 16, 0, 0);
      __builtin_amdgcn_global_load_lds((const __attribute__((address_space(1))) void*)gb,
                                       (__attribute__((address_space(3))) void*)lb, 16, 0, 0);
    }
    __syncthreads();
    s8v af[4], bfv[4];
#pragma unroll
    for (int m = 0; m < 4; ++m)
      af[m] = *reinterpret_cast<const s8v*>(As + (wr + m*16 + lr)*32 + lk);
#pragma unroll
    for (int n = 0; n < 4; ++n)
      bfv[n] = *reinterpret_cast<const s8v*>(Bs + (wc + n*16 + lr)*32 + lk);
#pragma unroll
    for (int m = 0; m < 4; ++m)
#pragma unroll
      for (int n = 0; n < 4; ++n)
        acc[m][n] = __builtin_amdgcn_mfma_f32_16x16x32_bf16(
            __builtin_bit_cast(b8v, af[m]), __builtin_bit_cast(b8v, bfv[n]),
            acc[m][n], 0, 0, 0);
    __syncthreads();
  }

  if (MODE == 2 && n0 >= 512) {
#pragma unroll
    for (int m = 0; m < 4; ++m) {
#pragma unroll
      for (int n = 0; n < 4; ++n) {
        const int col = n0 + wc + n*16 + lr - 512;
        const int row = m0 + wr + m*16 + (lane >> 4)*4;
        short4 o;
        o.x = f2bs(acc[m][n][0]); o.y = f2bs(acc[m][n][1]);
        o.z = f2bs(acc[m][n][2]); o.w = f2bs(acc[m][n][3]);
        *reinterpret_cast<short4*>(C2 + (size_t)col * M + row) = o;
      }
    }
  } else {
#pragma unroll
    for (int m = 0; m < 4; ++m) {
#pragma unroll
      for (int n = 0; n < 4; ++n) {
#pragma unroll
        for (int i = 0; i < 4; ++i) {
          const int row = m0 + wr + m*16 + (lane >> 4)*4 + i;
          const int col = n0 + wc + n*16 + lr;
          if (MODE == 1)
            reinterpret_cast<float*>(Cv)[(size_t)row * N + col] = acc[m][n][i];
          else if (MODE == 2)
            reinterpret_cast<short*>(Cv)[(size_t)row * 512 + col] = f2bs(acc[m][n][i]);
          else
            reinterpret_cast<short*>(Cv)[(size_t)row * N + col] = f2bs(acc[m][n][i]);
        }
      }
    }
  }
}

// ---------------- flash attention (32x32 swapped-operand form) ----------------
// grid: 512 blocks = 32 (b,h) x 16 q-blocks of 128 rows; 4 waves x 32 q-rows.
// CU-balance remap: the two blocks landing on one CU (bid, bid+256 under
// round-robin dispatch) get p summing to 15 -> uniform 34 kv-tiles per CU.
// S^T = mfma(K, Q): lane owns q-row (col = lane&31) -> in-register softmax.
// O^T = mfma(V^T, P^T): col = q -> lane-local rescale/normalize.
// C layout (32x32): col = lane&31, row = (reg&3) + 8*(reg>>2) + 4*(lane>>5).
__device__ __forceinline__ void stage_tile(short* KsBuf, short* VtBuf,
                                           const short* __restrict__ Kb,
                                           const short* __restrict__ Vtg,
                                           int bT, int kv0, int kvh,
                                           int tid, int wave) {
#pragma unroll
  for (int j = 0; j < 4; ++j) {
    const int f = j*256 + tid;
    const int row = f >> 4, cd = f & 15, cs = cd ^ (row & 7);
    const short* g = Kb + (size_t)(bT + kv0 + row)*512 + kvh*HD_ + cs*8;
    short* l = KsBuf + (j*256 + wave*64) * 8;
    __builtin_amdgcn_global_load_lds((const __attribute__((address_space(1))) void*)g,
                                     (__attribute__((address_space(3))) void*)l, 16, 0, 0);
  }
#pragma unroll
  for (int j = 0; j < 4; ++j) {
    const int f = j*256 + tid;
    const int d = f >> 3, cd = f & 7, cs = cd ^ (d & 7);
    const short* g = Vtg + (size_t)(kvh*HD_ + d)*M_ + bT + kv0 + cs*8;
    short* l = VtBuf + (j*256 + wave*64) * 8;
    __builtin_amdgcn_global_load_lds((const __attribute__((address_space(1))) void*)g,
                                     (__attribute__((address_space(3))) void*)l, 16, 0, 0);
  }
}

__global__ __launch_bounds__(256, 2) void attn_kernel(const short* __restrict__ Q,
                                                      const short* __restrict__ Kb,
                                                      const short* __restrict__ Vtg,
                                                      const int* __restrict__ ids,
                                                      short* __restrict__ AO) {
  __shared__ alignas(16) short Ks[2][64*128];   // keys row-major, chunk-swizzled
  __shared__ alignas(16) short Vt[2][128*64];   // V^T [d][key], chunk-swizzled

  const int bid = blockIdx.x;
  const int g   = bid & 31;
  const int gr  = bid >> 5;                     // 0..15
  const int p   = (gr < 8) ? (15 - gr) : (gr - 8);  // CU-pairs sum to 15
  const int h   = g & (H_-1);
  const int b   = g >> 4;
  const int kvh = h & (KV_-1);
  const int tid = threadIdx.x;
  const int wq  = tid >> 6;
  const int lane = tid & 63;
  const int ql  = lane & 31;
  const int hi  = lane >> 5;
  const int bT  = b * T_;
  const int q0  = p * 128;
  const int qrow = q0 + wq*32 + ql;             // q index within T
  const int nt  = 2*(p+1);
  const float SC = 0.08838834764831845f * 1.4426950408889634f;  // 1/sqrt(128)*log2(e)

  // Q fragments: qf[m] = Q[qrow][m*16 + hi*8 .. +7]
  s8v qf[8];
  const size_t qgbase = (size_t)(bT + qrow) * (H_*HD_) + h*HD_;
#pragma unroll
  for (int mm = 0; mm < 8; ++mm)
    qf[mm] = *reinterpret_cast<const s8v*>(Q + qgbase + mm*16 + hi*8);

  f16v oacc[4];
#pragma unroll
  for (int n = 0; n < 4; ++n) oacc[n] = (f16v)0.0f;
  float m_run = -1.0e30f, lsum = 0.0f;

  stage_tile(Ks[0], Vt[0], Kb, Vtg, bT, 0, kvh, tid, wq);
  int cur = 0;
  for (int t = 0; t < nt; ++t) {
    __syncthreads();                            // tile t staged (vmcnt drained)
    if (t + 1 < nt)
      stage_tile(Ks[cur^1], Vt[cur^1], Kb, Vtg, bT, (t+1)*64, kvh, tid, wq);
    const int kv0 = t * 64;
    const char* KsC = reinterpret_cast<const char*>(Ks[cur]);
    const char* VtC = reinterpret_cast<const char*>(Vt[cur]);

    const unsigned long long pmask = __ballot(ids[bT + kv0 + lane] != 0);

    // S^T = K Q^T : sacc[kb] covers keys kb*32..+31 (reg-rows) x 32 q (cols)
    f16v sacc[2];
    sacc[0] = (f16v)0.0f; sacc[1] = (f16v)0.0f;
    __builtin_amdgcn_s_setprio(1);
#pragma unroll
    for (int mm = 0; mm < 8; ++mm) {
#pragma unroll
      for (int kb = 0; kb < 2; ++kb) {
        const int row = kb*32 + ql;
        s8v kf = *reinterpret_cast<const s8v*>(KsC +
            ((row*256 + mm*32 + hi*16) ^ ((row & 7) << 4)));
        sacc[kb] = __builtin_amdgcn_mfma_f32_32x32x16_bf16(
            __builtin_bit_cast(b8v, kf), __builtin_bit_cast(b8v, qf[mm]), sacc[kb], 0, 0, 0);
      }
    }
    __builtin_amdgcn_s_setprio(0);

    // row max over superset (exact: consistent shift; masked zeroed post-exp)
    float mx = sacc[0][0];
#pragma unroll
    for (int r = 1; r < 16; ++r) mx = fmaxf(mx, sacc[0][r]);
#pragma unroll
    for (int r = 0; r < 16; ++r) mx = fmaxf(mx, sacc[1][r]);
    mx = fmaxf(mx, __shfl_xor(mx, 32));

    if (!__all(mx <= m_run + 20.0f)) {          // defer-max (T13)
      const float mn = fmaxf(m_run, mx);
      const float corr = exp2f((m_run - mn) * SC);
      lsum *= corr;
#pragma unroll
      for (int n = 0; n < 4; ++n)
#pragma unroll
        for (int r = 0; r < 16; ++r) oacc[n][r] *= corr;
      m_run = mn;
    }
    const float nm = -m_run * SC;
    const bool fast = (kv0 + 63 <= q0 + wq*32) && (pmask == ~0ull);

    float psum = 0.0f;
#pragma unroll
    for (int kb = 0; kb < 2; ++kb) {
      float pv[16];
#pragma unroll
      for (int r = 0; r < 16; ++r)
        pv[r] = exp2f(fmaf(sacc[kb][r], SC, nm));
      if (!fast) {
        const int th = qrow - kv0 - kb*32 - 4*hi;     // valid: C <= th
        const unsigned cw = (th >= 28) ? 0xffffffffu
                          : ((th < 0) ? 0u : ((2u << th) - 1u));
        const unsigned vm = cw & (unsigned)(pmask >> (kb*32 + 4*hi));
#pragma unroll
        for (int r = 0; r < 16; ++r) {
          const int C = (r & 3) + 8*(r >> 2);
          pv[r] = ((vm >> C) & 1u) ? pv[r] : 0.0f;
        }
      }
#pragma unroll
      for (int r = 0; r < 16; ++r) psum += pv[r];

      // P^T fragments: pack pairs to bf16, redistribute across lane^32 halves.
      const unsigned x0 = pack2(pv[0],  pv[1]),  x1 = pack2(pv[2],  pv[3]);
      const unsigned x2 = pack2(pv[4],  pv[5]),  x3 = pack2(pv[6],  pv[7]);
      const unsigned x4 = pack2(pv[8],  pv[9]),  x5 = pack2(pv[10], pv[11]);
      const unsigned x6 = pack2(pv[12], pv[13]), x7 = pack2(pv[14], pv[15]);
      const unsigned y0 = __shfl_xor(x0, 32), y1 = __shfl_xor(x1, 32);
      const unsigned y2 = __shfl_xor(x2, 32), y3 = __shfl_xor(x3, 32);
      const unsigned y4 = __shfl_xor(x4, 32), y5 = __shfl_xor(x5, 32);
      const unsigned y6 = __shfl_xor(x6, 32), y7 = __shfl_xor(x7, 32);
      u4v pw0, pw1;
      pw0[0] = hi ? y2 : x0;  pw0[1] = hi ? y3 : x1;   // s=0: keys hi*8+0..7
      pw0[2] = hi ? x2 : y0;  pw0[3] = hi ? x3 : y1;
      pw1[0] = hi ? y6 : x4;  pw1[1] = hi ? y7 : x5;   // s=1: keys 16+hi*8+0..7
      pw1[2] = hi ? x6 : y4;  pw1[3] = hi ? x7 : y5;

      __builtin_amdgcn_s_setprio(1);
#pragma unroll
      for (int s = 0; s < 2; ++s) {
        const b8v pf = __builtin_bit_cast(b8v, s ? pw1 : pw0);
        const int ks = 2*kb + s;
#pragma unroll
        for (int n = 0; n < 4; ++n) {
          const int d = n*32 + ql;
          s8v vf = *reinterpret_cast<const s8v*>(VtC +
              ((d*128 + ks*32 + hi*16) ^ ((d & 7) << 4)));
          oacc[n] = __builtin_amdgcn_mfma_f32_32x32x16_bf16(
              __builtin_bit_cast(b8v, vf), pf, oacc[n], 0, 0, 0);
        }
      }
      __builtin_amdgcn_s_setprio(0);
    }
    lsum += psum + __shfl_xor(psum, 32);
    cur ^= 1;
  }

  const float inv = 1.0f / fmaxf(lsum, 1.0e-37f);
  const size_t obase = (size_t)(bT + qrow) * (H_*HD_) + h*HD_;
#pragma unroll
  for (int n = 0; n < 4; ++n) {
#pragma unroll
    for (int j = 0; j < 4; ++j) {
      short4 o;
      o.x = f2bs(oacc[n][4*j+0] * inv);
      o.y = f2bs(oacc[n][4*j+1] * inv);
      o.z = f2bs(oacc[n][4*j+2] * inv);
      o.w = f2bs(oacc[n][4*j+3] * inv);
      *reinterpret_cast<short4*>(AO + obase + n*32 + 8*j + 4*hi) = o;
    }
  }
}

// ---------------- launcher ----------------
extern "C" void kernel_launch(void* const* d_in, const int* in_sizes, int n_in,
                              void* d_out, int out_size, void* d_ws, size_t ws_size,
                              hipStream_t stream) {
  const float* hs = (const float*)d_in[0];
  const int*  ids = (const int*)d_in[1];
  const float* Wq = (const float*)d_in[2];
  const float* Wk = (const float*)d_in[3];
  const float* Wv = (const float*)d_in[4];
  const float* Wo = (const float*)d_in[5];
  char* ws = (char*)d_ws;

  short* hsb = (short*)(ws);                          // 16 MiB, reused as AO
  short* WqT = (short*)(ws + (16u << 20));            // 8 MiB  [2048][2048]
  short* KVT = (short*)(ws + (24u << 20));            // 4 MiB  [1024][2048]
  short* WoT = (short*)(ws + (28u << 20));            // 8 MiB  [2048][2048]
  short* Qb  = (short*)(ws + (36u << 20));            // 16 MiB [4096][2048]
  short* Kb  = (short*)(ws + (52u << 20));            // 4 MiB  [4096][512]
  short* Vtg = (short*)(ws + (56u << 20));            // 4 MiB  [512][4096]
  short* AO  = hsb;
  float* out = (float*)d_out;

  cast_bf16_kernel<<<dim3((M_*D_/4 + 255)/256), dim3(256), 0, stream>>>(hs, hsb, M_*D_/4);
  dim3 tb(32, 8);
  tcast_kernel<<<dim3(2048/32, 2048/32), tb, 0, stream>>>(Wq, WqT, 2048, 2048);
  tcast_kernel<<<dim3(512/32, 2048/32),  tb, 0, stream>>>(Wk, KVT, 512, 2048);
  tcast_kernel<<<dim3(512/32, 2048/32),  tb, 0, stream>>>(Wv, KVT + (size_t)512*2048, 512, 2048);
  tcast_kernel<<<dim3(2048/32, 2048/32), tb, 0, stream>>>(Wo, WoT, 2048, 2048);

  gemm_bt_kernel<0><<<dim3(2048/128, 4096/128), dim3(256), 0, stream>>>(hsb, WqT, Qb, nullptr, 4096, 2048, 2048);
  gemm_bt_kernel<2><<<dim3(1024/128, 4096/128), dim3(256), 0, stream>>>(hsb, KVT, Kb, Vtg, 4096, 1024, 2048);

  attn_kernel<<<dim3(512), dim3(256), 0, stream>>>(Qb, Kb, Vtg, ids, AO);

  gemm_bt_kernel<1><<<dim3(2048/128, 4096/128), dim3(256), 0, stream>>>(AO, WoT, out, nullptr, 4096, 2048, 2048);
}

// Round 7
// 225.878 us; speedup vs baseline: 1.1914x; 1.1914x over previous
//
#include <hip/hip_runtime.h>

#define B_ 2
#define T_ 2048
#define D_ 2048
#define H_ 16
#define KV_ 4
#define HD_ 128
#define M_ (B_*T_)   // 4096

typedef __attribute__((ext_vector_type(8))) short s8v;
typedef __attribute__((ext_vector_type(4))) float f4v;
typedef __attribute__((ext_vector_type(16))) float f16v;
typedef __attribute__((ext_vector_type(8))) __bf16 b8v;
typedef __attribute__((ext_vector_type(4))) unsigned u4v;

__device__ __forceinline__ short f2bs(float f) {
  unsigned u = __builtin_bit_cast(unsigned, f);
  u += 0x7fffu + ((u >> 16) & 1u);
  return (short)(u >> 16);
}
// swap hi-half of x with lo-half of y (distinct values only! aliased operands
// coalesce to one register and corrupt — the R3 NaN)
__device__ __forceinline__ void plswap2(unsigned &x, unsigned &y) {
  asm volatile("v_permlane32_swap_b32 %0, %1" : "+v"(x), "+v"(y));
}
__device__ __forceinline__ unsigned cvtpk(float lo, float hi) {
  unsigned r;
  asm("v_cvt_pk_bf16_f32 %0, %1, %2" : "=v"(r) : "v"(lo), "v"(hi));
  return r;
}

// ---------------- elementwise fp32 -> bf16 cast ----------------
__global__ void cast_bf16_kernel(const float* __restrict__ in, short* __restrict__ out, int n4) {
  int i = blockIdx.x * 256 + threadIdx.x;
  if (i >= n4) return;
  float4 v = reinterpret_cast<const float4*>(in)[i];
  short4 o;
  o.x = f2bs(v.x); o.y = f2bs(v.y); o.z = f2bs(v.z); o.w = f2bs(v.w);
  reinterpret_cast<short4*>(out)[i] = o;
}

// ---------------- fused transpose+cast of all four weights ----------------
// Wq[2048][2048] -> WT rows 0..2047; Wk[2048][512] -> WT rows 2048..2559;
// Wv[2048][512] -> WT rows 2560..3071; Wo[2048][2048] -> WoT. All dst stride 2048.
__global__ void tcast_all_kernel(const float* __restrict__ Wq, const float* __restrict__ Wk,
                                 const float* __restrict__ Wv, const float* __restrict__ Wo,
                                 short* __restrict__ WT, short* __restrict__ WoT) {
  __shared__ float t[32][33];
  int bid = blockIdx.x;
  const float* W; short* dst; int N, rowoff;
  if (bid < 4096)      { W = Wq; dst = WT;  N = 2048; rowoff = 0;    }
  else if (bid < 5120) { W = Wk; dst = WT;  N = 512;  rowoff = 2048; bid -= 4096; }
  else if (bid < 6144) { W = Wv; dst = WT;  N = 512;  rowoff = 2560; bid -= 5120; }
  else                 { W = Wo; dst = WoT; N = 2048; rowoff = 0;    bid -= 6144; }
  const int nbl = N >> 5;
  const int nb = (bid % nbl) * 32, kb = (bid / nbl) * 32;
  const int tx = threadIdx.x, ty = threadIdx.y;
#pragma unroll
  for (int j = 0; j < 4; ++j)
    t[ty + j*8][tx] = W[(size_t)(kb + ty + j*8) * N + nb + tx];
  __syncthreads();
#pragma unroll
  for (int j = 0; j < 4; ++j)
    dst[(size_t)(rowoff + nb + ty + j*8) * 2048 + kb + tx] = f2bs(t[tx][ty + j*8]);
}

// ---------------- GEMM: C[M][N] = A[M][K](bf16) * BT[N][K](bf16)^T ----------------
// MODE 1: f32 row-major out (Cv).
// MODE 3: fused QKV split — n0<2048 -> Qv bf16 [M][2048]; n0<2560 -> Kv bf16 [M][512];
//         else -> V^T bf16 [512][M] (short4-packed rows).
template<int MODE>
__global__ __launch_bounds__(256) void gemm_bt_kernel(const short* __restrict__ A,
                                                      const short* __restrict__ BT,
                                                      void* __restrict__ Cv,
                                                      short* __restrict__ Kv,
                                                      short* __restrict__ Vt,
                                                      int M, int N, int K) {
  __shared__ alignas(16) short As[128*32];
  __shared__ alignas(16) short Bs[128*32];
  const int tid  = threadIdx.x;
  const int wave = tid >> 6;
  const int lane = tid & 63;
  const int lr = lane & 15;
  const int lk = (lane >> 4) * 8;
  const int m0 = blockIdx.y * 128;
  const int n0 = blockIdx.x * 128;
  const int wr = (wave >> 1) * 64;
  const int wc = (wave & 1) * 64;

  f4v acc[4][4];
#pragma unroll
  for (int m = 0; m < 4; ++m)
#pragma unroll
    for (int n = 0; n < 4; ++n) acc[m][n] = (f4v)0.0f;

  for (int k0 = 0; k0 < K; k0 += 32) {
#pragma unroll
    for (int j = 0; j < 2; ++j) {
      const int f = j*256 + tid;
      const int row = f >> 2, kc = f & 3;
      const short* ga = A  + (size_t)(m0 + row) * K + k0 + kc*8;
      const short* gb = BT + (size_t)(n0 + row) * K + k0 + kc*8;
      short* la = As + (j*256 + wave*64) * 8;
      short* lb = Bs + (j*256 + wave*64) * 8;
      __builtin_amdgcn_global_load_lds((const __attribute__((address_space(1))) void*)ga,
                                       (__attribute__((address_space(3))) void*)la, 16, 0, 0);
      __builtin_amdgcn_global_load_lds((const __attribute__((address_space(1))) void*)gb,
                                       (__attribute__((address_space(3))) void*)lb, 16, 0, 0);
    }
    __syncthreads();
    s8v af[4], bfv[4];
#pragma unroll
    for (int m = 0; m < 4; ++m)
      af[m] = *reinterpret_cast<const s8v*>(As + (wr + m*16 + lr)*32 + lk);
#pragma unroll
    for (int n = 0; n < 4; ++n)
      bfv[n] = *reinterpret_cast<const s8v*>(Bs + (wc + n*16 + lr)*32 + lk);
#pragma unroll
    for (int m = 0; m < 4; ++m)
#pragma unroll
      for (int n = 0; n < 4; ++n)
        acc[m][n] = __builtin_amdgcn_mfma_f32_16x16x32_bf16(
            __builtin_bit_cast(b8v, af[m]), __builtin_bit_cast(b8v, bfv[n]),
            acc[m][n], 0, 0, 0);
    __syncthreads();
  }

  if (MODE == 3 && n0 >= 2560) {
    // V^T epilogue: Vt[(col-2560)][row], 4 consecutive rows packed
#pragma unroll
    for (int m = 0; m < 4; ++m) {
#pragma unroll
      for (int n = 0; n < 4; ++n) {
        const int col = n0 + wc + n*16 + lr - 2560;
        const int row = m0 + wr + m*16 + (lane >> 4)*4;
        short4 o;
        o.x = f2bs(acc[m][n][0]); o.y = f2bs(acc[m][n][1]);
        o.z = f2bs(acc[m][n][2]); o.w = f2bs(acc[m][n][3]);
        *reinterpret_cast<short4*>(Vt + (size_t)col * M + row) = o;
      }
    }
  } else {
#pragma unroll
    for (int m = 0; m < 4; ++m) {
#pragma unroll
      for (int n = 0; n < 4; ++n) {
#pragma unroll
        for (int i = 0; i < 4; ++i) {
          const int row = m0 + wr + m*16 + (lane >> 4)*4 + i;
          const int col = n0 + wc + n*16 + lr;
          if (MODE == 1)
            reinterpret_cast<float*>(Cv)[(size_t)row * N + col] = acc[m][n][i];
          else if (col < 2048)
            reinterpret_cast<short*>(Cv)[(size_t)row * 2048 + col] = f2bs(acc[m][n][i]);
          else
            Kv[(size_t)row * 512 + (col - 2048)] = f2bs(acc[m][n][i]);
        }
      }
    }
  }
}

// ---------------- flash attention (32x32 swapped-operand form) ----------------
// grid: 512 blocks = 32 (b,h) x 16 q-blocks of 128 rows; 4 waves x 32 q-rows.
// CU-pair balance: p(gr) pairs sum to 15 under round-robin dispatch.
// S^T = mfma(K, Q): lane owns q-row (col = lane&31) -> in-register softmax.
// O^T = mfma(V^T, P^T). C layout: col=lane&31, row=(reg&3)+8*(reg>>2)+4*(lane>>5).
__device__ __forceinline__ void stage_tile(short* KsBuf, short* VtBuf,
                                           const short* __restrict__ Kb,
                                           const short* __restrict__ Vtg,
                                           int bT, int kv0, int kvh,
                                           int tid, int wave) {
#pragma unroll
  for (int j = 0; j < 4; ++j) {
    const int f = j*256 + tid;
    const int row = f >> 4, cd = f & 15, cs = cd ^ (row & 7);
    const short* g = Kb + (size_t)(bT + kv0 + row)*512 + kvh*HD_ + cs*8;
    short* l = KsBuf + (j*256 + wave*64) * 8;
    __builtin_amdgcn_global_load_lds((const __attribute__((address_space(1))) void*)g,
                                     (__attribute__((address_space(3))) void*)l, 16, 0, 0);
  }
#pragma unroll
  for (int j = 0; j < 4; ++j) {
    const int f = j*256 + tid;
    const int d = f >> 3, cd = f & 7, cs = cd ^ (d & 7);
    const short* g = Vtg + (size_t)(kvh*HD_ + d)*M_ + bT + kv0 + cs*8;
    short* l = VtBuf + (j*256 + wave*64) * 8;
    __builtin_amdgcn_global_load_lds((const __attribute__((address_space(1))) void*)g,
                                     (__attribute__((address_space(3))) void*)l, 16, 0, 0);
  }
}

__global__ __launch_bounds__(256, 2) void attn_kernel(const short* __restrict__ Q,
                                                      const short* __restrict__ Kb,
                                                      const short* __restrict__ Vtg,
                                                      const int* __restrict__ ids,
                                                      short* __restrict__ AO) {
  __shared__ alignas(16) short Ks[2][64*128];   // keys row-major, chunk-swizzled
  __shared__ alignas(16) short Vt[2][128*64];   // V^T [d][key], chunk-swizzled

  const int bid = blockIdx.x;
  const int g   = bid & 31;
  const int gr  = bid >> 5;                     // 0..15
  const int p   = (gr < 8) ? (15 - gr) : (gr - 8);  // CU-pairs sum to 15
  const int h   = g & (H_-1);
  const int b   = g >> 4;
  const int kvh = h & (KV_-1);
  const int tid = threadIdx.x;
  const int wq  = tid >> 6;
  const int lane = tid & 63;
  const int ql  = lane & 31;
  const int hi  = lane >> 5;
  const int bT  = b * T_;
  const int q0  = p * 128;
  const int qrow = q0 + wq*32 + ql;             // q index within T
  const int nt  = 2*(p+1);
  const float SC = 0.08838834764831845f * 1.4426950408889634f;  // 1/sqrt(128)*log2(e)

  // Q fragments: qf[m] = Q[qrow][m*16 + hi*8 .. +7]
  s8v qf[8];
  const size_t qgbase = (size_t)(bT + qrow) * (H_*HD_) + h*HD_;
#pragma unroll
  for (int mm = 0; mm < 8; ++mm)
    qf[mm] = *reinterpret_cast<const s8v*>(Q + qgbase + mm*16 + hi*8);

  f16v oacc[4];
#pragma unroll
  for (int n = 0; n < 4; ++n) oacc[n] = (f16v)0.0f;
  float m_run = -1.0e30f, lsum = 0.0f;

  stage_tile(Ks[0], Vt[0], Kb, Vtg, bT, 0, kvh, tid, wq);
  int cur = 0;
  for (int t = 0; t < nt; ++t) {
    __syncthreads();                            // tile t staged (vmcnt drained)
    if (t + 1 < nt)
      stage_tile(Ks[cur^1], Vt[cur^1], Kb, Vtg, bT, (t+1)*64, kvh, tid, wq);
    const int kv0 = t * 64;
    const char* KsC = reinterpret_cast<const char*>(Ks[cur]);
    const char* VtC = reinterpret_cast<const char*>(Vt[cur]);

    const unsigned long long pmask = __ballot(ids[bT + kv0 + lane] != 0);

    // S^T = K Q^T : sacc[kb] covers keys kb*32..+31 (reg-rows) x 32 q (cols)
    f16v sacc[2];
    sacc[0] = (f16v)0.0f; sacc[1] = (f16v)0.0f;
#pragma unroll
    for (int mm = 0; mm < 8; ++mm) {
#pragma unroll
      for (int kb = 0; kb < 2; ++kb) {
        const int row = kb*32 + ql;
        s8v kf = *reinterpret_cast<const s8v*>(KsC +
            ((row*256 + mm*32 + hi*16) ^ ((row & 7) << 4)));
        sacc[kb] = __builtin_amdgcn_mfma_f32_32x32x16_bf16(
            __builtin_bit_cast(b8v, kf), __builtin_bit_cast(b8v, qf[mm]), sacc[kb], 0, 0, 0);
      }
    }

    // row max over superset — tree reduction (depth 5), then cross-half
    float tm[16];
#pragma unroll
    for (int r = 0; r < 16; ++r) tm[r] = fmaxf(sacc[0][r], sacc[1][r]);
#pragma unroll
    for (int r = 0; r < 8; ++r) tm[r] = fmaxf(tm[r], tm[r+8]);
#pragma unroll
    for (int r = 0; r < 4; ++r) tm[r] = fmaxf(tm[r], tm[r+4]);
    tm[0] = fmaxf(fmaxf(tm[0], tm[1]), fmaxf(tm[2], tm[3]));
    const float mx = fmaxf(tm[0], __shfl_xor(tm[0], 32));

    if (!__all(mx <= m_run + 20.0f)) {          // defer-max (T13)
      const float mn = fmaxf(m_run, mx);
      const float corr = exp2f((m_run - mn) * SC);
      lsum *= corr;
#pragma unroll
      for (int n = 0; n < 4; ++n)
#pragma unroll
        for (int r = 0; r < 16; ++r) oacc[n][r] *= corr;
      m_run = mn;
    }
    const float nm = -m_run * SC;
    const bool fast = (kv0 + 63 <= q0 + wq*32) && (pmask == ~0ull);

    float psum = 0.0f;
#pragma unroll
    for (int kb = 0; kb < 2; ++kb) {
      float pv[16];
#pragma unroll
      for (int r = 0; r < 16; ++r)
        pv[r] = exp2f(fmaf(sacc[kb][r], SC, nm));
      if (!fast) {
        const int th = qrow - kv0 - kb*32 - 4*hi;     // valid: C <= th
        const unsigned cw = (th >= 28) ? 0xffffffffu
                          : ((th < 0) ? 0u : ((2u << th) - 1u));
        const unsigned vm = cw & (unsigned)(pmask >> (kb*32 + 4*hi));
#pragma unroll
        for (int r = 0; r < 16; ++r) {
          const int C = (r & 3) + 8*(r >> 2);
          pv[r] = ((vm >> C) & 1u) ? pv[r] : 0.0f;
        }
      }
      // psum tree (depth 4)
      float ps[8];
#pragma unroll
      for (int r = 0; r < 8; ++r) ps[r] = pv[r] + pv[r+8];
#pragma unroll
      for (int r = 0; r < 4; ++r) ps[r] += ps[r+4];
      psum += (ps[0] + ps[1]) + (ps[2] + ps[3]);

      // P^T fragments: cvt_pk to bf16 pairs, permlane32_swap redistributes
      // halves (VALU pipe — no LDS). One swap fills two output words.
      unsigned pa = cvtpk(pv[0],  pv[1]),  pb = cvtpk(pv[2],  pv[3]);
      unsigned pc = cvtpk(pv[4],  pv[5]),  pd = cvtpk(pv[6],  pv[7]);
      unsigned pe = cvtpk(pv[8],  pv[9]),  pf_ = cvtpk(pv[10], pv[11]);
      unsigned pg = cvtpk(pv[12], pv[13]), ph = cvtpk(pv[14], pv[15]);
      plswap2(pa, pc);  plswap2(pb, pd);
      plswap2(pe, pg);  plswap2(pf_, ph);
      u4v pw0 = {pa, pb, pc, pd};
      u4v pw1 = {pe, pf_, pg, ph};

#pragma unroll
      for (int s = 0; s < 2; ++s) {
        const b8v pf = __builtin_bit_cast(b8v, s ? pw1 : pw0);
        const int ks = 2*kb + s;
#pragma unroll
        for (int n = 0; n < 4; ++n) {
          const int d = n*32 + ql;
          s8v vf = *reinterpret_cast<const s8v*>(VtC +
              ((d*128 + ks*32 + hi*16) ^ ((d & 7) << 4)));
          oacc[n] = __builtin_amdgcn_mfma_f32_32x32x16_bf16(
              __builtin_bit_cast(b8v, vf), pf, oacc[n], 0, 0, 0);
        }
      }
    }
    lsum += psum + __shfl_xor(psum, 32);
    cur ^= 1;
  }

  const float inv = 1.0f / fmaxf(lsum, 1.0e-37f);
  const size_t obase = (size_t)(bT + qrow) * (H_*HD_) + h*HD_;
#pragma unroll
  for (int n = 0; n < 4; ++n) {
#pragma unroll
    for (int j = 0; j < 4; ++j) {
      short4 o;
      o.x = f2bs(oacc[n][4*j+0] * inv);
      o.y = f2bs(oacc[n][4*j+1] * inv);
      o.z = f2bs(oacc[n][4*j+2] * inv);
      o.w = f2bs(oacc[n][4*j+3] * inv);
      *reinterpret_cast<short4*>(AO + obase + n*32 + 8*j + 4*hi) = o;
    }
  }
}

// ---------------- launcher ----------------
extern "C" void kernel_launch(void* const* d_in, const int* in_sizes, int n_in,
                              void* d_out, int out_size, void* d_ws, size_t ws_size,
                              hipStream_t stream) {
  const float* hs = (const float*)d_in[0];
  const int*  ids = (const int*)d_in[1];
  const float* Wq = (const float*)d_in[2];
  const float* Wk = (const float*)d_in[3];
  const float* Wv = (const float*)d_in[4];
  const float* Wo = (const float*)d_in[5];
  char* ws = (char*)d_ws;

  short* hsb = (short*)(ws);                          // 16 MiB, reused as AO
  short* WT  = (short*)(ws + (16u << 20));            // 12 MiB [3072][2048] (Wq|Wk|Wv)^T
  short* WoT = (short*)(ws + (28u << 20));            // 8 MiB  [2048][2048]
  short* Qb  = (short*)(ws + (36u << 20));            // 16 MiB [4096][2048]
  short* Kb  = (short*)(ws + (52u << 20));            // 4 MiB  [4096][512]
  short* Vtg = (short*)(ws + (56u << 20));            // 4 MiB  [512][4096]
  short* AO  = hsb;
  float* out = (float*)d_out;

  cast_bf16_kernel<<<dim3((M_*D_/4 + 255)/256), dim3(256), 0, stream>>>(hs, hsb, M_*D_/4);
  tcast_all_kernel<<<dim3(10240), dim3(32, 8), 0, stream>>>(Wq, Wk, Wv, Wo, WT, WoT);

  // fused QKV projection: [4096][3072] split into Qb / Kb / Vtg
  gemm_bt_kernel<3><<<dim3(3072/128, 4096/128), dim3(256), 0, stream>>>(
      hsb, WT, Qb, Kb, Vtg, 4096, 3072, 2048);

  attn_kernel<<<dim3(512), dim3(256), 0, stream>>>(Qb, Kb, Vtg, ids, AO);

  gemm_bt_kernel<1><<<dim3(2048/128, 4096/128), dim3(256), 0, stream>>>(
      AO, WoT, out, nullptr, nullptr, 4096, 2048, 2048);
}

// Round 8
// 211.680 us; speedup vs baseline: 1.2713x; 1.0671x over previous
//
#include <hip/hip_runtime.h>

#define B_ 2
#define T_ 2048
#define D_ 2048
#define H_ 16
#define KV_ 4
#define HD_ 128
#define M_ (B_*T_)   // 4096

typedef __attribute__((ext_vector_type(8))) short s8v;
typedef __attribute__((ext_vector_type(4))) float f4v;
typedef __attribute__((ext_vector_type(16))) float f16v;
typedef __attribute__((ext_vector_type(8))) __bf16 b8v;
typedef __attribute__((ext_vector_type(4))) unsigned u4v;

__device__ __forceinline__ short f2bs(float f) {
  unsigned u = __builtin_bit_cast(unsigned, f);
  u += 0x7fffu + ((u >> 16) & 1u);
  return (short)(u >> 16);
}
// swap hi-half of x with lo-half of y (distinct values only! aliased operands
// coalesce to one register and corrupt — the R3 NaN)
__device__ __forceinline__ void plswap2(unsigned &x, unsigned &y) {
  asm volatile("v_permlane32_swap_b32 %0, %1" : "+v"(x), "+v"(y));
}
__device__ __forceinline__ unsigned cvtpk(float lo, float hi) {
  unsigned r;
  asm("v_cvt_pk_bf16_f32 %0, %1, %2" : "=v"(r) : "v"(lo), "v"(hi));
  return r;
}

// ---------------- elementwise fp32 -> bf16 cast ----------------
__global__ void cast_bf16_kernel(const float* __restrict__ in, short* __restrict__ out, int n4) {
  int i = blockIdx.x * 256 + threadIdx.x;
  if (i >= n4) return;
  float4 v = reinterpret_cast<const float4*>(in)[i];
  short4 o;
  o.x = f2bs(v.x); o.y = f2bs(v.y); o.z = f2bs(v.z); o.w = f2bs(v.w);
  reinterpret_cast<short4*>(out)[i] = o;
}

// ---------------- fused transpose+cast of all four weights ----------------
// Wq[2048][2048] -> WT rows 0..2047; Wk[2048][512] -> WT rows 2048..2559;
// Wv[2048][512] -> WT rows 2560..3071; Wo[2048][2048] -> WoT. All dst stride 2048.
__global__ void tcast_all_kernel(const float* __restrict__ Wq, const float* __restrict__ Wk,
                                 const float* __restrict__ Wv, const float* __restrict__ Wo,
                                 short* __restrict__ WT, short* __restrict__ WoT) {
  __shared__ float t[32][33];
  int bid = blockIdx.x;
  const float* W; short* dst; int N, rowoff;
  if (bid < 4096)      { W = Wq; dst = WT;  N = 2048; rowoff = 0;    }
  else if (bid < 5120) { W = Wk; dst = WT;  N = 512;  rowoff = 2048; bid -= 4096; }
  else if (bid < 6144) { W = Wv; dst = WT;  N = 512;  rowoff = 2560; bid -= 5120; }
  else                 { W = Wo; dst = WoT; N = 2048; rowoff = 0;    bid -= 6144; }
  const int nbl = N >> 5;
  const int nb = (bid % nbl) * 32, kb = (bid / nbl) * 32;
  const int tx = threadIdx.x, ty = threadIdx.y;
#pragma unroll
  for (int j = 0; j < 4; ++j)
    t[ty + j*8][tx] = W[(size_t)(kb + ty + j*8) * N + nb + tx];
  __syncthreads();
#pragma unroll
  for (int j = 0; j < 4; ++j)
    dst[(size_t)(rowoff + nb + ty + j*8) * 2048 + kb + tx] = f2bs(t[tx][ty + j*8]);
}

// ---------------- GEMM: C[M][N] = A[M][K](bf16) * BT[N][K](bf16)^T ----------------
// Double-buffered LDS, single barrier per K-step (attn-proven pattern): the
// next tile's global_load_lds is issued right after the barrier and stays in
// flight across the whole compute phase; the NEXT barrier drains it.
// MODE 1: f32 row-major out (Cv).
// MODE 3: fused QKV split — n0<2048 -> Qv bf16 [M][2048]; n0<2560 -> Kv bf16 [M][512];
//         else -> V^T bf16 [512][M] (short4-packed rows).
template<int MODE>
__global__ __launch_bounds__(256) void gemm_bt_kernel(const short* __restrict__ A,
                                                      const short* __restrict__ BT,
                                                      void* __restrict__ Cv,
                                                      short* __restrict__ Kv,
                                                      short* __restrict__ Vt,
                                                      int M, int N, int K) {
  __shared__ alignas(16) short As[2][128*32];
  __shared__ alignas(16) short Bs[2][128*32];
  const int tid  = threadIdx.x;
  const int wave = tid >> 6;
  const int lane = tid & 63;
  const int lr = lane & 15;
  const int lk = (lane >> 4) * 8;
  const int m0 = blockIdx.y * 128;
  const int n0 = blockIdx.x * 128;
  const int wr = (wave >> 1) * 64;
  const int wc = (wave & 1) * 64;

  // staging addresses (per-thread constants)
  const int srow = tid >> 2, skc = tid & 3;
  const short* gaBase = A  + (size_t)(m0 + srow) * K + skc*8;
  const short* gbBase = BT + (size_t)(n0 + srow) * K + skc*8;
  const short* gaBase2 = A  + (size_t)(m0 + 64 + srow) * K + skc*8;
  const short* gbBase2 = BT + (size_t)(n0 + 64 + srow) * K + skc*8;
  const int ldsOff  = (wave*64) * 8;
  const int ldsOff2 = (256 + wave*64) * 8;

  f4v acc[4][4];
#pragma unroll
  for (int m = 0; m < 4; ++m)
#pragma unroll
    for (int n = 0; n < 4; ++n) acc[m][n] = (f4v)0.0f;

  // prologue: stage tile 0 into buffer 0
  {
    __builtin_amdgcn_global_load_lds((const __attribute__((address_space(1))) void*)gaBase,
        (__attribute__((address_space(3))) void*)(&As[0][0] + ldsOff), 16, 0, 0);
    __builtin_amdgcn_global_load_lds((const __attribute__((address_space(1))) void*)gbBase,
        (__attribute__((address_space(3))) void*)(&Bs[0][0] + ldsOff), 16, 0, 0);
    __builtin_amdgcn_global_load_lds((const __attribute__((address_space(1))) void*)gaBase2,
        (__attribute__((address_space(3))) void*)(&As[0][0] + ldsOff2), 16, 0, 0);
    __builtin_amdgcn_global_load_lds((const __attribute__((address_space(1))) void*)gbBase2,
        (__attribute__((address_space(3))) void*)(&Bs[0][0] + ldsOff2), 16, 0, 0);
  }

  int cur = 0;
  for (int k0 = 0; k0 < K; k0 += 32) {
    __syncthreads();   // drains in-flight DMA for tile k0 (vmcnt0) + sync
    if (k0 + 32 < K) {
      const int kn = k0 + 32;
      short* a1 = &As[cur^1][0];
      short* b1 = &Bs[cur^1][0];
      __builtin_amdgcn_global_load_lds((const __attribute__((address_space(1))) void*)(gaBase + kn),
          (__attribute__((address_space(3))) void*)(a1 + ldsOff), 16, 0, 0);
      __builtin_amdgcn_global_load_lds((const __attribute__((address_space(1))) void*)(gbBase + kn),
          (__attribute__((address_space(3))) void*)(b1 + ldsOff), 16, 0, 0);
      __builtin_amdgcn_global_load_lds((const __attribute__((address_space(1))) void*)(gaBase2 + kn),
          (__attribute__((address_space(3))) void*)(a1 + ldsOff2), 16, 0, 0);
      __builtin_amdgcn_global_load_lds((const __attribute__((address_space(1))) void*)(gbBase2 + kn),
          (__attribute__((address_space(3))) void*)(b1 + ldsOff2), 16, 0, 0);
    }
    const short* Ac = &As[cur][0];
    const short* Bc = &Bs[cur][0];
    s8v af[4], bfv[4];
#pragma unroll
    for (int m = 0; m < 4; ++m)
      af[m] = *reinterpret_cast<const s8v*>(Ac + (wr + m*16 + lr)*32 + lk);
#pragma unroll
    for (int n = 0; n < 4; ++n)
      bfv[n] = *reinterpret_cast<const s8v*>(Bc + (wc + n*16 + lr)*32 + lk);
#pragma unroll
    for (int m = 0; m < 4; ++m)
#pragma unroll
      for (int n = 0; n < 4; ++n)
        acc[m][n] = __builtin_amdgcn_mfma_f32_16x16x32_bf16(
            __builtin_bit_cast(b8v, af[m]), __builtin_bit_cast(b8v, bfv[n]),
            acc[m][n], 0, 0, 0);
    cur ^= 1;
  }

  if (MODE == 3 && n0 >= 2560) {
    // V^T epilogue: Vt[(col-2560)][row], 4 consecutive rows packed
#pragma unroll
    for (int m = 0; m < 4; ++m) {
#pragma unroll
      for (int n = 0; n < 4; ++n) {
        const int col = n0 + wc + n*16 + lr - 2560;
        const int row = m0 + wr + m*16 + (lane >> 4)*4;
        short4 o;
        o.x = f2bs(acc[m][n][0]); o.y = f2bs(acc[m][n][1]);
        o.z = f2bs(acc[m][n][2]); o.w = f2bs(acc[m][n][3]);
        *reinterpret_cast<short4*>(Vt + (size_t)col * M + row) = o;
      }
    }
  } else {
#pragma unroll
    for (int m = 0; m < 4; ++m) {
#pragma unroll
      for (int n = 0; n < 4; ++n) {
#pragma unroll
        for (int i = 0; i < 4; ++i) {
          const int row = m0 + wr + m*16 + (lane >> 4)*4 + i;
          const int col = n0 + wc + n*16 + lr;
          if (MODE == 1)
            reinterpret_cast<float*>(Cv)[(size_t)row * N + col] = acc[m][n][i];
          else if (col < 2048)
            reinterpret_cast<short*>(Cv)[(size_t)row * 2048 + col] = f2bs(acc[m][n][i]);
          else
            Kv[(size_t)row * 512 + (col - 2048)] = f2bs(acc[m][n][i]);
        }
      }
    }
  }
}

// ---------------- flash attention (32x32 swapped-operand form) ----------------
// grid: 512 blocks = 32 (b,h) x 16 q-blocks of 128 rows; 4 waves x 32 q-rows.
// CU-pair balance: p(gr) pairs sum to 15 under round-robin dispatch.
// S^T = mfma(K, Q): lane owns q-row (col = lane&31) -> in-register softmax.
// O^T = mfma(V^T, P^T). C layout: col=lane&31, row=(reg&3)+8*(reg>>2)+4*(lane>>5).
__device__ __forceinline__ void stage_tile(short* KsBuf, short* VtBuf,
                                           const short* __restrict__ Kb,
                                           const short* __restrict__ Vtg,
                                           int bT, int kv0, int kvh,
                                           int tid, int wave) {
#pragma unroll
  for (int j = 0; j < 4; ++j) {
    const int f = j*256 + tid;
    const int row = f >> 4, cd = f & 15, cs = cd ^ (row & 7);
    const short* g = Kb + (size_t)(bT + kv0 + row)*512 + kvh*HD_ + cs*8;
    short* l = KsBuf + (j*256 + wave*64) * 8;
    __builtin_amdgcn_global_load_lds((const __attribute__((address_space(1))) void*)g,
                                     (__attribute__((address_space(3))) void*)l, 16, 0, 0);
  }
#pragma unroll
  for (int j = 0; j < 4; ++j) {
    const int f = j*256 + tid;
    const int d = f >> 3, cd = f & 7, cs = cd ^ (d & 7);
    const short* g = Vtg + (size_t)(kvh*HD_ + d)*M_ + bT + kv0 + cs*8;
    short* l = VtBuf + (j*256 + wave*64) * 8;
    __builtin_amdgcn_global_load_lds((const __attribute__((address_space(1))) void*)g,
                                     (__attribute__((address_space(3))) void*)l, 16, 0, 0);
  }
}

__global__ __launch_bounds__(256, 2) void attn_kernel(const short* __restrict__ Q,
                                                      const short* __restrict__ Kb,
                                                      const short* __restrict__ Vtg,
                                                      const int* __restrict__ ids,
                                                      short* __restrict__ AO) {
  __shared__ alignas(16) short Ks[2][64*128];   // keys row-major, chunk-swizzled
  __shared__ alignas(16) short Vt[2][128*64];   // V^T [d][key], chunk-swizzled

  const int bid = blockIdx.x;
  const int g   = bid & 31;
  const int gr  = bid >> 5;                     // 0..15
  const int p   = (gr < 8) ? (15 - gr) : (gr - 8);  // CU-pairs sum to 15
  const int h   = g & (H_-1);
  const int b   = g >> 4;
  const int kvh = h & (KV_-1);
  const int tid = threadIdx.x;
  const int wq  = tid >> 6;
  const int lane = tid & 63;
  const int ql  = lane & 31;
  const int hi  = lane >> 5;
  const int bT  = b * T_;
  const int q0  = p * 128;
  const int qrow = q0 + wq*32 + ql;             // q index within T
  const int nt  = 2*(p+1);
  const float SC = 0.08838834764831845f * 1.4426950408889634f;  // 1/sqrt(128)*log2(e)

  // Q fragments: qf[m] = Q[qrow][m*16 + hi*8 .. +7]
  s8v qf[8];
  const size_t qgbase = (size_t)(bT + qrow) * (H_*HD_) + h*HD_;
#pragma unroll
  for (int mm = 0; mm < 8; ++mm)
    qf[mm] = *reinterpret_cast<const s8v*>(Q + qgbase + mm*16 + hi*8);

  f16v oacc[4];
#pragma unroll
  for (int n = 0; n < 4; ++n) oacc[n] = (f16v)0.0f;
  float m_run = -1.0e30f, lsum = 0.0f;

  stage_tile(Ks[0], Vt[0], Kb, Vtg, bT, 0, kvh, tid, wq);
  int cur = 0;
  for (int t = 0; t < nt; ++t) {
    __syncthreads();                            // tile t staged (vmcnt drained)
    if (t + 1 < nt)
      stage_tile(Ks[cur^1], Vt[cur^1], Kb, Vtg, bT, (t+1)*64, kvh, tid, wq);
    const int kv0 = t * 64;
    const char* KsC = reinterpret_cast<const char*>(Ks[cur]);
    const char* VtC = reinterpret_cast<const char*>(Vt[cur]);

    const unsigned long long pmask = __ballot(ids[bT + kv0 + lane] != 0);

    // S^T = K Q^T : sacc[kb] covers keys kb*32..+31 (reg-rows) x 32 q (cols)
    f16v sacc[2];
    sacc[0] = (f16v)0.0f; sacc[1] = (f16v)0.0f;
#pragma unroll
    for (int mm = 0; mm < 8; ++mm) {
#pragma unroll
      for (int kb = 0; kb < 2; ++kb) {
        const int row = kb*32 + ql;
        s8v kf = *reinterpret_cast<const s8v*>(KsC +
            ((row*256 + mm*32 + hi*16) ^ ((row & 7) << 4)));
        sacc[kb] = __builtin_amdgcn_mfma_f32_32x32x16_bf16(
            __builtin_bit_cast(b8v, kf), __builtin_bit_cast(b8v, qf[mm]), sacc[kb], 0, 0, 0);
      }
    }

    // row max over superset — tree reduction (depth 5), then cross-half
    float tm[16];
#pragma unroll
    for (int r = 0; r < 16; ++r) tm[r] = fmaxf(sacc[0][r], sacc[1][r]);
#pragma unroll
    for (int r = 0; r < 8; ++r) tm[r] = fmaxf(tm[r], tm[r+8]);
#pragma unroll
    for (int r = 0; r < 4; ++r) tm[r] = fmaxf(tm[r], tm[r+4]);
    tm[0] = fmaxf(fmaxf(tm[0], tm[1]), fmaxf(tm[2], tm[3]));
    const float mx = fmaxf(tm[0], __shfl_xor(tm[0], 32));

    if (!__all(mx <= m_run + 20.0f)) {          // defer-max (T13)
      const float mn = fmaxf(m_run, mx);
      const float corr = exp2f((m_run - mn) * SC);
      lsum *= corr;
#pragma unroll
      for (int n = 0; n < 4; ++n)
#pragma unroll
        for (int r = 0; r < 16; ++r) oacc[n][r] *= corr;
      m_run = mn;
    }
    const float nm = -m_run * SC;
    const bool fast = (kv0 + 63 <= q0 + wq*32) && (pmask == ~0ull);

    float psum = 0.0f;
#pragma unroll
    for (int kb = 0; kb < 2; ++kb) {
      float pv[16];
#pragma unroll
      for (int r = 0; r < 16; ++r)
        pv[r] = exp2f(fmaf(sacc[kb][r], SC, nm));
      if (!fast) {
        const int th = qrow - kv0 - kb*32 - 4*hi;     // valid: C <= th
        const unsigned cw = (th >= 28) ? 0xffffffffu
                          : ((th < 0) ? 0u : ((2u << th) - 1u));
        const unsigned vm = cw & (unsigned)(pmask >> (kb*32 + 4*hi));
#pragma unroll
        for (int r = 0; r < 16; ++r) {
          const int C = (r & 3) + 8*(r >> 2);
          pv[r] = ((vm >> C) & 1u) ? pv[r] : 0.0f;
        }
      }
      // psum tree (depth 4)
      float ps[8];
#pragma unroll
      for (int r = 0; r < 8; ++r) ps[r] = pv[r] + pv[r+8];
#pragma unroll
      for (int r = 0; r < 4; ++r) ps[r] += ps[r+4];
      psum += (ps[0] + ps[1]) + (ps[2] + ps[3]);

      // P^T fragments: cvt_pk to bf16 pairs, permlane32_swap redistributes
      // halves (VALU pipe — no LDS). One swap fills two output words.
      unsigned pa = cvtpk(pv[0],  pv[1]),  pb = cvtpk(pv[2],  pv[3]);
      unsigned pc = cvtpk(pv[4],  pv[5]),  pd = cvtpk(pv[6],  pv[7]);
      unsigned pe = cvtpk(pv[8],  pv[9]),  pf_ = cvtpk(pv[10], pv[11]);
      unsigned pg = cvtpk(pv[12], pv[13]), ph = cvtpk(pv[14], pv[15]);
      plswap2(pa, pc);  plswap2(pb, pd);
      plswap2(pe, pg);  plswap2(pf_, ph);
      u4v pw0 = {pa, pb, pc, pd};
      u4v pw1 = {pe, pf_, pg, ph};

#pragma unroll
      for (int s = 0; s < 2; ++s) {
        const b8v pf = __builtin_bit_cast(b8v, s ? pw1 : pw0);
        const int ks = 2*kb + s;
#pragma unroll
        for (int n = 0; n < 4; ++n) {
          const int d = n*32 + ql;
          s8v vf = *reinterpret_cast<const s8v*>(VtC +
              ((d*128 + ks*32 + hi*16) ^ ((d & 7) << 4)));
          oacc[n] = __builtin_amdgcn_mfma_f32_32x32x16_bf16(
              __builtin_bit_cast(b8v, vf), pf, oacc[n], 0, 0, 0);
        }
      }
    }
    lsum += psum + __shfl_xor(psum, 32);
    cur ^= 1;
  }

  const float inv = 1.0f / fmaxf(lsum, 1.0e-37f);
  const size_t obase = (size_t)(bT + qrow) * (H_*HD_) + h*HD_;
#pragma unroll
  for (int n = 0; n < 4; ++n) {
#pragma unroll
    for (int j = 0; j < 4; ++j) {
      short4 o;
      o.x = f2bs(oacc[n][4*j+0] * inv);
      o.y = f2bs(oacc[n][4*j+1] * inv);
      o.z = f2bs(oacc[n][4*j+2] * inv);
      o.w = f2bs(oacc[n][4*j+3] * inv);
      *reinterpret_cast<short4*>(AO + obase + n*32 + 8*j + 4*hi) = o;
    }
  }
}

// ---------------- launcher ----------------
extern "C" void kernel_launch(void* const* d_in, const int* in_sizes, int n_in,
                              void* d_out, int out_size, void* d_ws, size_t ws_size,
                              hipStream_t stream) {
  const float* hs = (const float*)d_in[0];
  const int*  ids = (const int*)d_in[1];
  const float* Wq = (const float*)d_in[2];
  const float* Wk = (const float*)d_in[3];
  const float* Wv = (const float*)d_in[4];
  const float* Wo = (const float*)d_in[5];
  char* ws = (char*)d_ws;

  short* hsb = (short*)(ws);                          // 16 MiB, reused as AO
  short* WT  = (short*)(ws + (16u << 20));            // 12 MiB [3072][2048] (Wq|Wk|Wv)^T
  short* WoT = (short*)(ws + (28u << 20));            // 8 MiB  [2048][2048]
  short* Qb  = (short*)(ws + (36u << 20));            // 16 MiB [4096][2048]
  short* Kb  = (short*)(ws + (52u << 20));            // 4 MiB  [4096][512]
  short* Vtg = (short*)(ws + (56u << 20));            // 4 MiB  [512][4096]
  short* AO  = hsb;
  float* out = (float*)d_out;

  cast_bf16_kernel<<<dim3((M_*D_/4 + 255)/256), dim3(256), 0, stream>>>(hs, hsb, M_*D_/4);
  tcast_all_kernel<<<dim3(10240), dim3(32, 8), 0, stream>>>(Wq, Wk, Wv, Wo, WT, WoT);

  // fused QKV projection: [4096][3072] split into Qb / Kb / Vtg
  gemm_bt_kernel<3><<<dim3(3072/128, 4096/128), dim3(256), 0, stream>>>(
      hsb, WT, Qb, Kb, Vtg, 4096, 3072, 2048);

  attn_kernel<<<dim3(512), dim3(256), 0, stream>>>(Qb, Kb, Vtg, ids, AO);

  gemm_bt_kernel<1><<<dim3(2048/128, 4096/128), dim3(256), 0, stream>>>(
      AO, WoT, out, nullptr, nullptr, 4096, 2048, 2048);
}